// Round 1
// 1925.434 us; speedup vs baseline: 1.4298x; 1.4298x over previous
//
#include <hip/hip_runtime.h>
#include <math.h>

// Problem constants (fixed by the reference setup)
#define NTOK  65536      // B*T = 16*4096
#define DDIM  256
#define KCODE 1024
#define LLAY  8
#define NQ    (NTOK*DDIM)        // 16777216 floats: quantized output
#define LOSS_OFF NQ              // 1 float: total loss
#define IDX_OFF  (NQ+1)          // 524288 floats: indices [B,T,L] as float

// ws layout (bytes):
//   [0, 4MB)     E_hi  bf16, SWIZZLED into MFMA B-fragment order:
//                element (((l*64 + t)*8 + ks)*64 + lane)*8 + j
//                  = Ehi_linear[l][t*16 + (lane&15)][ks*32 + (lane>>4)*8 + j]
//   [4MB, 8MB)   E_lo  bf16, same swizzle
//   [8MB, +32KB) ekk   f32  [l][k]  = ||e||^2 (f64-accumulated, narrowed)
#define EHI_OFF 0
#define ELO_OFF (LLAY*KCODE*DDIM)          // in ushort elements: 2097152
#define EKK_BYTE_OFF 8388608

typedef __attribute__((ext_vector_type(8))) short short8;   // 8 bf16 (4 VGPR)
typedef __attribute__((ext_vector_type(4))) float f32x4;    // MFMA C/D frag

__device__ __forceinline__ unsigned short f2bf(float f) {   // RTNE f32->bf16
    unsigned u = __float_as_uint(f);
    u = u + 0x7fffu + ((u >> 16) & 1u);
    return (unsigned short)(u >> 16);
}
__device__ __forceinline__ float bf2f(unsigned short h) {
    return __uint_as_float(((unsigned)h) << 16);
}

// ---------------------------------------------------------------------------
// Prep kernel A: split E f32 -> bf16 hi/lo, written in swizzled MFMA
// B-fragment order so the main kernel's loads are fully coalesced streams.
// One thread per (l, t, ks, lane): 8*64*8*64 = 262144 threads.
// ---------------------------------------------------------------------------
__global__ __launch_bounds__(256) void rvq_prep_swz(const float* __restrict__ E,
                                                    unsigned short* __restrict__ Ehi,
                                                    unsigned short* __restrict__ Elo,
                                                    float* __restrict__ out) {
    int gid  = blockIdx.x * 256 + threadIdx.x;   // 1024 blocks * 256
    int lane = gid & 63;
    int ks   = (gid >> 6) & 7;
    int t    = (gid >> 9) & 63;
    int l    = gid >> 15;
    int code = t * 16 + (lane & 15);
    int d    = ks * 32 + (lane >> 4) * 8;
    const float* src = E + ((size_t)(l * KCODE + code)) * DDIM + d;
    float4 a = *(const float4*)(src);
    float4 b = *(const float4*)(src + 4);
    float f[8] = {a.x, a.y, a.z, a.w, b.x, b.y, b.z, b.w};
    short8 h, lo;
#pragma unroll
    for (int j = 0; j < 8; ++j) {
        unsigned short hh = f2bf(f[j]);
        h[j]  = (short)hh;
        lo[j] = (short)f2bf(f[j] - bf2f(hh));
    }
    *(short8*)(Ehi + (size_t)gid * 8) = h;
    *(short8*)(Elo + (size_t)gid * 8) = lo;
    if (gid == 0) out[LOSS_OFF] = 0.0f;
}

// ---------------------------------------------------------------------------
// Prep kernel B: per-code ||e||^2 (f32 squares, f64 accumulate, narrow).
// Validated bitwise-compatible with the np reference in round 2.
// ---------------------------------------------------------------------------
__global__ __launch_bounds__(256) void rvq_ekk(const float* __restrict__ E,
                                               float* __restrict__ ekk) {
    int gid = blockIdx.x * 256 + threadIdx.x;   // 8192 = L*K
    const float4* rowp = (const float4*)(E + (size_t)gid * DDIM);
    double s = 0.0;
#pragma unroll 8
    for (int i = 0; i < 64; ++i) {
        float4 v = rowp[i];
        float p0 = v.x * v.x, p1 = v.y * v.y, p2 = v.z * v.z, p3 = v.w * v.w;
        s += (double)p0; s += (double)p1; s += (double)p2; s += (double)p3;
    }
    ekk[gid] = (float)s;
}

// ---------------------------------------------------------------------------
// top-2 merge with (score, index) lexicographic order (np.argmin ties)
// ---------------------------------------------------------------------------
__device__ __forceinline__ void merge2(float& s1, int& k1, float& s2, int& k2,
                                       float ps1, int pk1, float ps2, int pk2) {
    bool pb = (ps1 < s1) || (ps1 == s1 && pk1 < k1);
    if (pb) {
        bool mb = (s1 < ps2) || (s1 == ps2 && k1 < pk2);
        float ns2 = mb ? s1 : ps2; int nk2 = mb ? k1 : pk2;
        s1 = ps1; k1 = pk1; s2 = ns2; k2 = nk2;
    } else {
        bool mb = (ps1 < s2) || (ps1 == s2 && pk1 < k2);
        if (mb) { s2 = ps1; k2 = pk1; }
    }
}

// ---------------------------------------------------------------------------
// Main kernel: 64 tokens/block, 4 waves.
//   wave w: token-half th=w&1 (32 tokens, 2 MFMA tiles), code-half ch=w>>1 (512)
//   approx scores via bf16x3 MFMA (hh+hl+lh) -> per-lane top-2 -> lane merge ->
//   4 candidates/token -> exact f32-chain rescore (bitwise np semantics) ->
//   winner -> residual update in LDS (exact straight-through f32 ops).
//   B-fragments now come from the swizzled Ehi/Elo: each load is a coalesced
//   contiguous 1KB segment (base + lane*16B), 8KB linear stream per c-tile.
// ---------------------------------------------------------------------------
__global__ __launch_bounds__(256, 2) void rvq_main(const float* __restrict__ x,
                                                   const float* __restrict__ E,
                                                   const unsigned short* __restrict__ Ehi,
                                                   const unsigned short* __restrict__ Elo,
                                                   const float* __restrict__ ekk,
                                                   float* __restrict__ out) {
    __shared__ __align__(16) float  Rt[64 * 260];   // residual f32 [tok][260pad]
    __shared__ double Ad[256];                      // A_n partial sums
    __shared__ float4 cand[128];                    // [tok][ch]: s1,k1,s2,k2
    __shared__ float  Af[64];                       // per-token ||r||^2 (f32)
    __shared__ int    kw[64];                       // winning code per token
    __shared__ float  lred[4];                      // per-wave loss partials

    const int tid  = threadIdx.x;
    const int lane = tid & 63;
    const int wv   = tid >> 6;
    const int th   = wv & 1;       // token half
    const int ch   = wv >> 1;      // code half
    const int col  = lane & 15;    // MFMA n / m index within tile
    const int quad = lane >> 4;    // MFMA k-chunk selector
    const int m0   = blockIdx.x * 64;

    // ---- load residual = x into LDS (row-major, pad 260) ----
#pragma unroll
    for (int u = 0; u < 16; ++u) {
        int id4 = u * 256 + tid;          // 4096 float4
        int mm  = id4 >> 6;
        int d4  = (id4 & 63) << 2;
        float4 v = *(const float4*)(x + (size_t)(m0 + mm) * DDIM + d4);
        *(float4*)(&Rt[mm * 260 + d4]) = v;
    }

    float lacc = 0.f;

    for (int l = 0; l < LLAY; ++l) {
        const float* El = E + (size_t)l * KCODE * DDIM;
        __syncthreads();   // Rt stable (prev layer update done)

        // ---- A_m = sum_d fl32(r^2), f64-accurate, narrowed to f32 ----
        {
            int m = tid >> 2, c = tid & 3;
            const float* rr = &Rt[m * 260 + c * 64];
            double sa = 0.0;
#pragma unroll 4
            for (int q = 0; q < 16; ++q) {
                float4 v = *(const float4*)(rr + q * 4);
                float p0 = v.x * v.x, p1 = v.y * v.y, p2 = v.z * v.z, p3 = v.w * v.w;
                sa += (double)p0; sa += (double)p1; sa += (double)p2; sa += (double)p3;
            }
            Ad[tid] = sa;
        }
        __syncthreads();
        if (tid < 64) {
            double a = Ad[tid * 4] + Ad[tid * 4 + 1] + Ad[tid * 4 + 2] + Ad[tid * 4 + 3];
            Af[tid] = (float)a;
        }
        __syncthreads();

        // ---- per-lane A values for the 8 (tile,reg) accumulator rows ----
        float Ai[2][4];
#pragma unroll
        for (int tt = 0; tt < 2; ++tt)
#pragma unroll
            for (int g = 0; g < 4; ++g)
                Ai[tt][g] = Af[th * 32 + tt * 16 + quad * 4 + g];

        // ---- build A-frag cache (bf16 hi/lo) for full K from Rt ----
        short8 ah[2][8], al[2][8];
#pragma unroll
        for (int tt = 0; tt < 2; ++tt) {
            const float* rrow = &Rt[(th * 32 + tt * 16 + col) * 260];
#pragma unroll
            for (int ks = 0; ks < 8; ++ks) {
                float4 p = *(const float4*)(rrow + ks * 32 + quad * 8);
                float4 q = *(const float4*)(rrow + ks * 32 + quad * 8 + 4);
                float f[8] = {p.x, p.y, p.z, p.w, q.x, q.y, q.z, q.w};
#pragma unroll
                for (int j = 0; j < 8; ++j) {
                    unsigned short h = f2bf(f[j]);
                    ah[tt][ks][j] = (short)h;
                    al[tt][ks][j] = (short)f2bf(f[j] - bf2f(h));
                }
            }
        }

        // ---- approx scoring: 32 code-tiles of 16, top-2 per lane-stream ----
        float ts1[2][4], ts2[2][4];
        int   tc1[2][4], tc2[2][4];
#pragma unroll
        for (int tt = 0; tt < 2; ++tt)
#pragma unroll
            for (int g = 0; g < 4; ++g) {
                ts1[tt][g] = INFINITY; ts2[tt][g] = INFINITY;
                tc1[tt][g] = 0x7fff;   tc2[tt][g] = 0x7fff;
            }

        const int co = ch * 512;
        // swizzled base for this (layer, code-half): tile index t = ch*32 + c
        const unsigned short* bh0 =
            Ehi + (((size_t)l * 64 + (size_t)ch * 32) * 8 * 64) * 8 + (size_t)lane * 8;
        const unsigned short* bl0 =
            Elo + (((size_t)l * 64 + (size_t)ch * 32) * 8 * 64) * 8 + (size_t)lane * 8;

        for (int c = 0; c < 32; ++c) {
            const int code = co + c * 16 + col;
            float ekv = ekk[l * KCODE + code];
            // per-tile stride: 8 ks * 64 lanes * 8 ushorts = 4096 ushorts (8KB)
            const unsigned short* bh_p = bh0 + (size_t)c * 4096;
            const unsigned short* bl_p = bl0 + (size_t)c * 4096;

            short8 bh[8], bl[8];
#pragma unroll
            for (int ks = 0; ks < 8; ++ks) bh[ks] = *(const short8*)(bh_p + ks * 512);
#pragma unroll
            for (int ks = 0; ks < 8; ++ks) bl[ks] = *(const short8*)(bl_p + ks * 512);

            f32x4 acc0 = {0.f, 0.f, 0.f, 0.f};
            f32x4 acc1 = {0.f, 0.f, 0.f, 0.f};
#pragma unroll
            for (int ks = 0; ks < 8; ++ks) {
                acc0 = __builtin_amdgcn_mfma_f32_16x16x32_bf16(ah[0][ks], bh[ks], acc0, 0, 0, 0);
                acc1 = __builtin_amdgcn_mfma_f32_16x16x32_bf16(ah[1][ks], bh[ks], acc1, 0, 0, 0);
                acc0 = __builtin_amdgcn_mfma_f32_16x16x32_bf16(ah[0][ks], bl[ks], acc0, 0, 0, 0);
                acc1 = __builtin_amdgcn_mfma_f32_16x16x32_bf16(ah[1][ks], bl[ks], acc1, 0, 0, 0);
                acc0 = __builtin_amdgcn_mfma_f32_16x16x32_bf16(al[0][ks], bh[ks], acc0, 0, 0, 0);
                acc1 = __builtin_amdgcn_mfma_f32_16x16x32_bf16(al[1][ks], bh[ks], acc1, 0, 0, 0);
            }

#pragma unroll
            for (int tt = 0; tt < 2; ++tt)
#pragma unroll
                for (int g = 0; g < 4; ++g) {
                    float v = tt ? acc1[g] : acc0[g];
                    float s = fmaf(-2.f, v, Ai[tt][g] + ekv);
                    if (s < ts1[tt][g]) {
                        ts2[tt][g] = ts1[tt][g]; tc2[tt][g] = tc1[tt][g];
                        ts1[tt][g] = s;          tc1[tt][g] = c;
                    } else if (s < ts2[tt][g]) {
                        ts2[tt][g] = s; tc2[tt][g] = c;
                    }
                }
        }

        // ---- convert tile-codes to global code indices ----
        int ik1[2][4], ik2[2][4];
#pragma unroll
        for (int tt = 0; tt < 2; ++tt)
#pragma unroll
            for (int g = 0; g < 4; ++g) {
                ik1[tt][g] = co + (tc1[tt][g] << 4) + col;
                ik2[tt][g] = co + (tc2[tt][g] << 4) + col;
            }

        // ---- merge top-2 across the 16 cols (lanes differing in bits 0..3) ----
#pragma unroll
        for (int off = 1; off <= 8; off <<= 1) {
#pragma unroll
            for (int tt = 0; tt < 2; ++tt)
#pragma unroll
                for (int g = 0; g < 4; ++g) {
                    float os1 = __shfl_xor(ts1[tt][g], off, 64);
                    int   ok1 = __shfl_xor(ik1[tt][g], off, 64);
                    float os2 = __shfl_xor(ts2[tt][g], off, 64);
                    int   ok2 = __shfl_xor(ik2[tt][g], off, 64);
                    merge2(ts1[tt][g], ik1[tt][g], ts2[tt][g], ik2[tt][g],
                           os1, ok1, os2, ok2);
                }
        }
        if (col == 0) {
#pragma unroll
            for (int tt = 0; tt < 2; ++tt)
#pragma unroll
                for (int g = 0; g < 4; ++g) {
                    int tokl = th * 32 + tt * 16 + quad * 4 + g;
                    cand[tokl * 2 + ch] = make_float4(ts1[tt][g], __int_as_float(ik1[tt][g]),
                                                      ts2[tt][g], __int_as_float(ik2[tt][g]));
                }
        }
        __syncthreads();

        // ---- exact f32 rescore of the 4 candidates (bitwise np semantics) ----
        {
            int m = tid >> 2, j = tid & 3;
            float4 cd = cand[m * 2 + (j >> 1)];
            int myk = (j & 1) ? __float_as_int(cd.w) : __float_as_int(cd.y);
            const float* erow = El + (size_t)myk * DDIM;
            const float* rrow = &Rt[m * 260];
            float M = 0.f;
#pragma unroll 8
            for (int q = 0; q < 64; ++q) {     // ascending-d single fma chain
                float4 e4 = *(const float4*)(erow + q * 4);
                float4 r4 = *(const float4*)(rrow + q * 4);
                M = fmaf(r4.x, e4.x, M);
                M = fmaf(r4.y, e4.y, M);
                M = fmaf(r4.z, e4.z, M);
                M = fmaf(r4.w, e4.w, M);
            }
            float u = Af[m] + ekk[l * KCODE + myk];   // fl32(A + B)
            float s = fmaf(-2.f, M, u);               // fl32(u - 2M)
#pragma unroll
            for (int off = 1; off <= 2; off <<= 1) {
                float os = __shfl_xor(s, off, 64);
                int   ok = __shfl_xor(myk, off, 64);
                if ((os < s) || (os == s && ok < myk)) { s = os; myk = ok; }
            }
            if (j == 0) {
                kw[m] = myk;
                out[IDX_OFF + (size_t)(m0 + m) * LLAY + l] = (float)myk;
            }
        }
        __syncthreads();

        // ---- residual update (exact straight-through f32 ops) + loss ----
        {
            int m  = tid >> 2;
            int ds = (tid & 3) * 64;
            int kwm = kw[m];
            const float* erow = El + (size_t)kwm * DDIM;
            const float* xrow = x  + (size_t)(m0 + m) * DDIM;
            float*       orow = out + (size_t)(m0 + m) * DDIM;
            float*       rrow = &Rt[m * 260];
#pragma unroll 4
            for (int q = 0; q < 16; ++q) {
                int d = ds + q * 4;
                float4 e4 = *(const float4*)(erow + d);
                float4 r4 = *(const float4*)(rrow + d);
                float qv[4] = {e4.x, e4.y, e4.z, e4.w};
                float rv[4] = {r4.x, r4.y, r4.z, r4.w};
                float rn[4];
#pragma unroll
                for (int t = 0; t < 4; ++t) {
                    float d1  = qv[t] - rv[t];   // fl(q - r)  (loss term)
                    float qst = rv[t] + d1;      // fl(r + d1) (straight-through)
                    rn[t]     = rv[t] - qst;     // fl(r - q_st)
                    lacc = fmaf(d1, d1, lacc);
                }
                *(float4*)(rrow + d) = make_float4(rn[0], rn[1], rn[2], rn[3]);
                if (l == LLAY - 1) {
                    float4 x4 = *(const float4*)(xrow + d);
                    *(float4*)(orow + d) =
                        make_float4(x4.x - rn[0], x4.y - rn[1], x4.z - rn[2], x4.w - rn[3]);
                }
            }
        }
    }

    // ---- loss reduction: wave -> block -> global atomic ----
#pragma unroll
    for (int off = 32; off > 0; off >>= 1) lacc += __shfl_down(lacc, off, 64);
    __syncthreads();
    if ((tid & 63) == 0) lred[tid >> 6] = lacc;
    __syncthreads();
    if (tid == 0) {
        float t = lred[0] + lred[1] + lred[2] + lred[3];
        atomicAdd(out + LOSS_OFF, t * (0.25f / 16777216.0f));
    }
}

// ---------------------------------------------------------------------------
extern "C" void kernel_launch(void* const* d_in, const int* in_sizes, int n_in,
                              void* d_out, int out_size, void* d_ws, size_t ws_size,
                              hipStream_t stream) {
    const float* x  = (const float*)d_in[0];
    const float* E  = (const float*)d_in[1];
    float* out = (float*)d_out;
    unsigned short* Ehi = (unsigned short*)d_ws;
    unsigned short* Elo = Ehi + ELO_OFF;
    float* ekkp = (float*)((char*)d_ws + EKK_BYTE_OFF);   // needs ~8.42 MB ws

    rvq_prep_swz<<<dim3(1024), dim3(256), 0, stream>>>(E, Ehi, Elo, out);
    rvq_ekk<<<dim3(32), dim3(256), 0, stream>>>(E, ekkp);
    rvq_main<<<dim3(1024), dim3(256), 0, stream>>>(x, E, Ehi, Elo, ekkp, out);
}

// Round 2
// 1787.167 us; speedup vs baseline: 1.5404x; 1.0774x over previous
//
#include <hip/hip_runtime.h>
#include <math.h>

// Problem constants (fixed by the reference setup)
#define NTOK  65536      // B*T = 16*4096
#define DDIM  256
#define KCODE 1024
#define LLAY  8
#define NQ    (NTOK*DDIM)        // 16777216 floats: quantized output
#define LOSS_OFF NQ              // 1 float: total loss
#define IDX_OFF  (NQ+1)          // 524288 floats: indices [B,T,L] as float

// ws layout (bytes):
//   [0, 4MB)     E_hi  bf16, SWIZZLED into MFMA B-fragment order:
//                element (((l*64 + t)*8 + ks)*64 + lane)*8 + j
//                  = Ehi_linear[l][t*16 + (lane&15)][ks*32 + (lane>>4)*8 + j]
//   [4MB, 8MB)   E_lo  bf16, same swizzle
//   [8MB, +32KB) ekk   f32  [l][k]  = ||e||^2 (f64-accumulated, narrowed)
#define EHI_OFF 0
#define ELO_OFF (LLAY*KCODE*DDIM)          // in ushort elements: 2097152
#define EKK_BYTE_OFF 8388608

typedef __attribute__((ext_vector_type(8))) short short8;   // 8 bf16 (4 VGPR)
typedef __attribute__((ext_vector_type(4))) float f32x4;    // MFMA C/D frag

__device__ __forceinline__ unsigned short f2bf(float f) {   // RTNE f32->bf16
    unsigned u = __float_as_uint(f);
    u = u + 0x7fffu + ((u >> 16) & 1u);
    return (unsigned short)(u >> 16);
}
__device__ __forceinline__ float bf2f(unsigned short h) {
    return __uint_as_float(((unsigned)h) << 16);
}

// ---------------------------------------------------------------------------
// Prep kernel A: split E f32 -> bf16 hi/lo, written in swizzled MFMA
// B-fragment order so the main kernel's loads are fully coalesced streams.
// One thread per (l, t, ks, lane): 8*64*8*64 = 262144 threads.
// ---------------------------------------------------------------------------
__global__ __launch_bounds__(256) void rvq_prep_swz(const float* __restrict__ E,
                                                    unsigned short* __restrict__ Ehi,
                                                    unsigned short* __restrict__ Elo,
                                                    float* __restrict__ out) {
    int gid  = blockIdx.x * 256 + threadIdx.x;   // 1024 blocks * 256
    int lane = gid & 63;
    int ks   = (gid >> 6) & 7;
    int t    = (gid >> 9) & 63;
    int l    = gid >> 15;
    int code = t * 16 + (lane & 15);
    int d    = ks * 32 + (lane >> 4) * 8;
    const float* src = E + ((size_t)(l * KCODE + code)) * DDIM + d;
    float4 a = *(const float4*)(src);
    float4 b = *(const float4*)(src + 4);
    float f[8] = {a.x, a.y, a.z, a.w, b.x, b.y, b.z, b.w};
    short8 h, lo;
#pragma unroll
    for (int j = 0; j < 8; ++j) {
        unsigned short hh = f2bf(f[j]);
        h[j]  = (short)hh;
        lo[j] = (short)f2bf(f[j] - bf2f(hh));
    }
    *(short8*)(Ehi + (size_t)gid * 8) = h;
    *(short8*)(Elo + (size_t)gid * 8) = lo;
    if (gid == 0) out[LOSS_OFF] = 0.0f;
}

// ---------------------------------------------------------------------------
// Prep kernel B: per-code ||e||^2 (f32 squares, f64 accumulate, narrow).
// Validated bitwise-compatible with the np reference in round 2.
// ---------------------------------------------------------------------------
__global__ __launch_bounds__(256) void rvq_ekk(const float* __restrict__ E,
                                               float* __restrict__ ekk) {
    int gid = blockIdx.x * 256 + threadIdx.x;   // 8192 = L*K
    const float4* rowp = (const float4*)(E + (size_t)gid * DDIM);
    double s = 0.0;
#pragma unroll 8
    for (int i = 0; i < 64; ++i) {
        float4 v = rowp[i];
        float p0 = v.x * v.x, p1 = v.y * v.y, p2 = v.z * v.z, p3 = v.w * v.w;
        s += (double)p0; s += (double)p1; s += (double)p2; s += (double)p3;
    }
    ekk[gid] = (float)s;
}

// ---------------------------------------------------------------------------
// top-2 merge with (score, index) lexicographic order (np.argmin ties)
// ---------------------------------------------------------------------------
__device__ __forceinline__ void merge2(float& s1, int& k1, float& s2, int& k2,
                                       float ps1, int pk1, float ps2, int pk2) {
    bool pb = (ps1 < s1) || (ps1 == s1 && pk1 < k1);
    if (pb) {
        bool mb = (s1 < ps2) || (s1 == ps2 && k1 < pk2);
        float ns2 = mb ? s1 : ps2; int nk2 = mb ? k1 : pk2;
        s1 = ps1; k1 = pk1; s2 = ns2; k2 = nk2;
    } else {
        bool mb = (ps1 < s2) || (ps1 == s2 && pk1 < k2);
        if (mb) { s2 = ps1; k2 = pk1; }
    }
}

// ---------------------------------------------------------------------------
// Main kernel: 64 tokens/block, 4 waves.
//   wave w: token-half th=w&1 (32 tokens, 2 MFMA tiles), code-half ch=w>>1 (512)
//   approx scores via bf16x3 MFMA (hh+hl+lh) -> per-lane top-2 -> lane merge ->
//   4 candidates/token -> exact f32-chain rescore (bitwise np semantics) ->
//   winner -> residual update in LDS (exact straight-through f32 ops).
//   Scoring B-frags stream linearly through a 4-slot register rotation with
//   3-step prefetch lead: b-liveness is 32 VGPR (was 64), killing the scratch
//   spills that produced ~800MB of anomalous HBM writes, while hiding L2
//   latency under the MFMA block and top-2 update.
// ---------------------------------------------------------------------------
__global__ __launch_bounds__(256, 2) void rvq_main(const float* __restrict__ x,
                                                   const float* __restrict__ E,
                                                   const unsigned short* __restrict__ Ehi,
                                                   const unsigned short* __restrict__ Elo,
                                                   const float* __restrict__ ekk,
                                                   float* __restrict__ out) {
    __shared__ __align__(16) float  Rt[64 * 260];   // residual f32 [tok][260pad]
    __shared__ double Ad[256];                      // A_n partial sums
    __shared__ float4 cand[128];                    // [tok][ch]: s1,k1,s2,k2
    __shared__ float  Af[64];                       // per-token ||r||^2 (f32)
    __shared__ int    kw[64];                       // winning code per token
    __shared__ float  lred[4];                      // per-wave loss partials

    const int tid  = threadIdx.x;
    const int lane = tid & 63;
    const int wv   = tid >> 6;
    const int th   = wv & 1;       // token half
    const int ch   = wv >> 1;      // code half
    const int col  = lane & 15;    // MFMA n / m index within tile
    const int quad = lane >> 4;    // MFMA k-chunk selector
    const int m0   = blockIdx.x * 64;

    // ---- load residual = x into LDS (row-major, pad 260) ----
#pragma unroll
    for (int u = 0; u < 16; ++u) {
        int id4 = u * 256 + tid;          // 4096 float4
        int mm  = id4 >> 6;
        int d4  = (id4 & 63) << 2;
        float4 v = *(const float4*)(x + (size_t)(m0 + mm) * DDIM + d4);
        *(float4*)(&Rt[mm * 260 + d4]) = v;
    }

    float lacc = 0.f;

    for (int l = 0; l < LLAY; ++l) {
        const float* El = E + (size_t)l * KCODE * DDIM;
        __syncthreads();   // Rt stable (prev layer update done)

        // ---- A_m = sum_d fl32(r^2), f64-accurate, narrowed to f32 ----
        {
            int m = tid >> 2, c = tid & 3;
            const float* rr = &Rt[m * 260 + c * 64];
            double sa = 0.0;
#pragma unroll 4
            for (int q = 0; q < 16; ++q) {
                float4 v = *(const float4*)(rr + q * 4);
                float p0 = v.x * v.x, p1 = v.y * v.y, p2 = v.z * v.z, p3 = v.w * v.w;
                sa += (double)p0; sa += (double)p1; sa += (double)p2; sa += (double)p3;
            }
            Ad[tid] = sa;
        }
        __syncthreads();
        if (tid < 64) {
            double a = Ad[tid * 4] + Ad[tid * 4 + 1] + Ad[tid * 4 + 2] + Ad[tid * 4 + 3];
            Af[tid] = (float)a;
        }
        __syncthreads();

        // ---- per-lane A values for the 8 (tile,reg) accumulator rows ----
        float Ai[2][4];
#pragma unroll
        for (int tt = 0; tt < 2; ++tt)
#pragma unroll
            for (int g = 0; g < 4; ++g)
                Ai[tt][g] = Af[th * 32 + tt * 16 + quad * 4 + g];

        // ---- build A-frag cache (bf16 hi/lo) for full K from Rt ----
        short8 ah[2][8], al[2][8];
#pragma unroll
        for (int tt = 0; tt < 2; ++tt) {
            const float* rrow = &Rt[(th * 32 + tt * 16 + col) * 260];
#pragma unroll
            for (int ks = 0; ks < 8; ++ks) {
                float4 p = *(const float4*)(rrow + ks * 32 + quad * 8);
                float4 q = *(const float4*)(rrow + ks * 32 + quad * 8 + 4);
                float f[8] = {p.x, p.y, p.z, p.w, q.x, q.y, q.z, q.w};
#pragma unroll
                for (int j = 0; j < 8; ++j) {
                    unsigned short h = f2bf(f[j]);
                    ah[tt][ks][j] = (short)h;
                    al[tt][ks][j] = (short)f2bf(f[j] - bf2f(h));
                }
            }
        }

        // ---- approx scoring: 32 code-tiles of 16, top-2 per lane-stream ----
        float ts1[2][4], ts2[2][4];
        int   tc1[2][4], tc2[2][4];
#pragma unroll
        for (int tt = 0; tt < 2; ++tt)
#pragma unroll
            for (int g = 0; g < 4; ++g) {
                ts1[tt][g] = INFINITY; ts2[tt][g] = INFINITY;
                tc1[tt][g] = 0x7fff;   tc2[tt][g] = 0x7fff;
            }

        const int co = ch * 512;
        // linear swizzled stream: step = c*8 + ks, 512 ushorts (1KB) per step
        const unsigned short* ph =
            Ehi + ((size_t)(l * 64 + ch * 32) * 4096) + (size_t)lane * 8;
        const unsigned short* pl =
            Elo + ((size_t)(l * 64 + ch * 32) * 4096) + (size_t)lane * 8;

        // 4-slot rotation, 3-step prefetch lead. Slot (s%4) holds step s.
        short8 BH[4], BL[4];
        BH[0] = *(const short8*)(ph);           BL[0] = *(const short8*)(pl);
        BH[1] = *(const short8*)(ph + 512);     BL[1] = *(const short8*)(pl + 512);
        BH[2] = *(const short8*)(ph + 1024);    BL[2] = *(const short8*)(pl + 1024);

        for (int c = 0; c < 32; ++c) {
            const int code = co + c * 16 + col;
            float ekv = ekk[l * KCODE + code];

            f32x4 acc0 = {0.f, 0.f, 0.f, 0.f};
            f32x4 acc1 = {0.f, 0.f, 0.f, 0.f};
#pragma unroll
            for (int ks = 0; ks < 8; ++ks) {
                const int pf = (ks + 3) & 3;     // prefetch slot (compile-time)
                const int cs = ks & 3;           // consume slot (compile-time)
                // prefetch step ks+3 (crosses into next tile at ks>=5; the
                // stream is linear so the pointer math is uniform; worst-case
                // 3KB tail overrun lands in the adjacent ws region, unused)
                BH[pf] = *(const short8*)(ph + (ks + 3) * 512);
                BL[pf] = *(const short8*)(pl + (ks + 3) * 512);
                acc0 = __builtin_amdgcn_mfma_f32_16x16x32_bf16(ah[0][ks], BH[cs], acc0, 0, 0, 0);
                acc1 = __builtin_amdgcn_mfma_f32_16x16x32_bf16(ah[1][ks], BH[cs], acc1, 0, 0, 0);
                acc0 = __builtin_amdgcn_mfma_f32_16x16x32_bf16(ah[0][ks], BL[cs], acc0, 0, 0, 0);
                acc1 = __builtin_amdgcn_mfma_f32_16x16x32_bf16(ah[1][ks], BL[cs], acc1, 0, 0, 0);
                acc0 = __builtin_amdgcn_mfma_f32_16x16x32_bf16(al[0][ks], BH[cs], acc0, 0, 0, 0);
                acc1 = __builtin_amdgcn_mfma_f32_16x16x32_bf16(al[1][ks], BH[cs], acc1, 0, 0, 0);
            }
            ph += 4096; pl += 4096;

#pragma unroll
            for (int tt = 0; tt < 2; ++tt)
#pragma unroll
                for (int g = 0; g < 4; ++g) {
                    float v = tt ? acc1[g] : acc0[g];
                    float s = fmaf(-2.f, v, Ai[tt][g] + ekv);
                    if (s < ts1[tt][g]) {
                        ts2[tt][g] = ts1[tt][g]; tc2[tt][g] = tc1[tt][g];
                        ts1[tt][g] = s;          tc1[tt][g] = c;
                    } else if (s < ts2[tt][g]) {
                        ts2[tt][g] = s; tc2[tt][g] = c;
                    }
                }
        }

        // ---- convert tile-codes to global code indices ----
        int ik1[2][4], ik2[2][4];
#pragma unroll
        for (int tt = 0; tt < 2; ++tt)
#pragma unroll
            for (int g = 0; g < 4; ++g) {
                ik1[tt][g] = co + (tc1[tt][g] << 4) + col;
                ik2[tt][g] = co + (tc2[tt][g] << 4) + col;
            }

        // ---- merge top-2 across the 16 cols (lanes differing in bits 0..3) ----
#pragma unroll
        for (int off = 1; off <= 8; off <<= 1) {
#pragma unroll
            for (int tt = 0; tt < 2; ++tt)
#pragma unroll
                for (int g = 0; g < 4; ++g) {
                    float os1 = __shfl_xor(ts1[tt][g], off, 64);
                    int   ok1 = __shfl_xor(ik1[tt][g], off, 64);
                    float os2 = __shfl_xor(ts2[tt][g], off, 64);
                    int   ok2 = __shfl_xor(ik2[tt][g], off, 64);
                    merge2(ts1[tt][g], ik1[tt][g], ts2[tt][g], ik2[tt][g],
                           os1, ok1, os2, ok2);
                }
        }
        if (col == 0) {
#pragma unroll
            for (int tt = 0; tt < 2; ++tt)
#pragma unroll
                for (int g = 0; g < 4; ++g) {
                    int tokl = th * 32 + tt * 16 + quad * 4 + g;
                    cand[tokl * 2 + ch] = make_float4(ts1[tt][g], __int_as_float(ik1[tt][g]),
                                                      ts2[tt][g], __int_as_float(ik2[tt][g]));
                }
        }
        __syncthreads();

        // ---- exact f32 rescore of the 4 candidates (bitwise np semantics) ----
        {
            int m = tid >> 2, j = tid & 3;
            float4 cd = cand[m * 2 + (j >> 1)];
            int myk = (j & 1) ? __float_as_int(cd.w) : __float_as_int(cd.y);
            const float* erow = El + (size_t)myk * DDIM;
            const float* rrow = &Rt[m * 260];
            float M = 0.f;
#pragma unroll 8
            for (int q = 0; q < 64; ++q) {     // ascending-d single fma chain
                float4 e4 = *(const float4*)(erow + q * 4);
                float4 r4 = *(const float4*)(rrow + q * 4);
                M = fmaf(r4.x, e4.x, M);
                M = fmaf(r4.y, e4.y, M);
                M = fmaf(r4.z, e4.z, M);
                M = fmaf(r4.w, e4.w, M);
            }
            float u = Af[m] + ekk[l * KCODE + myk];   // fl32(A + B)
            float s = fmaf(-2.f, M, u);               // fl32(u - 2M)
#pragma unroll
            for (int off = 1; off <= 2; off <<= 1) {
                float os = __shfl_xor(s, off, 64);
                int   ok = __shfl_xor(myk, off, 64);
                if ((os < s) || (os == s && ok < myk)) { s = os; myk = ok; }
            }
            if (j == 0) {
                kw[m] = myk;
                out[IDX_OFF + (size_t)(m0 + m) * LLAY + l] = (float)myk;
            }
        }
        __syncthreads();

        // ---- residual update (exact straight-through f32 ops) + loss ----
        {
            int m  = tid >> 2;
            int ds = (tid & 3) * 64;
            int kwm = kw[m];
            const float* erow = El + (size_t)kwm * DDIM;
            const float* xrow = x  + (size_t)(m0 + m) * DDIM;
            float*       orow = out + (size_t)(m0 + m) * DDIM;
            float*       rrow = &Rt[m * 260];
#pragma unroll 4
            for (int q = 0; q < 16; ++q) {
                int d = ds + q * 4;
                float4 e4 = *(const float4*)(erow + d);
                float4 r4 = *(const float4*)(rrow + d);
                float qv[4] = {e4.x, e4.y, e4.z, e4.w};
                float rv[4] = {r4.x, r4.y, r4.z, r4.w};
                float rn[4];
#pragma unroll
                for (int t = 0; t < 4; ++t) {
                    float d1  = qv[t] - rv[t];   // fl(q - r)  (loss term)
                    float qst = rv[t] + d1;      // fl(r + d1) (straight-through)
                    rn[t]     = rv[t] - qst;     // fl(r - q_st)
                    lacc = fmaf(d1, d1, lacc);
                }
                *(float4*)(rrow + d) = make_float4(rn[0], rn[1], rn[2], rn[3]);
                if (l == LLAY - 1) {
                    float4 x4 = *(const float4*)(xrow + d);
                    *(float4*)(orow + d) =
                        make_float4(x4.x - rn[0], x4.y - rn[1], x4.z - rn[2], x4.w - rn[3]);
                }
            }
        }
    }

    // ---- loss reduction: wave -> block -> global atomic ----
#pragma unroll
    for (int off = 32; off > 0; off >>= 1) lacc += __shfl_down(lacc, off, 64);
    __syncthreads();
    if ((tid & 63) == 0) lred[tid >> 6] = lacc;
    __syncthreads();
    if (tid == 0) {
        float t = lred[0] + lred[1] + lred[2] + lred[3];
        atomicAdd(out + LOSS_OFF, t * (0.25f / 16777216.0f));
    }
}

// ---------------------------------------------------------------------------
extern "C" void kernel_launch(void* const* d_in, const int* in_sizes, int n_in,
                              void* d_out, int out_size, void* d_ws, size_t ws_size,
                              hipStream_t stream) {
    const float* x  = (const float*)d_in[0];
    const float* E  = (const float*)d_in[1];
    float* out = (float*)d_out;
    unsigned short* Ehi = (unsigned short*)d_ws;
    unsigned short* Elo = Ehi + ELO_OFF;
    float* ekkp = (float*)((char*)d_ws + EKK_BYTE_OFF);   // needs ~8.42 MB ws

    rvq_prep_swz<<<dim3(1024), dim3(256), 0, stream>>>(E, Ehi, Elo, out);
    rvq_ekk<<<dim3(32), dim3(256), 0, stream>>>(E, ekkp);
    rvq_main<<<dim3(1024), dim3(256), 0, stream>>>(x, E, Ehi, Elo, ekkp, out);
}